// Round 3
// baseline (148.101 us; speedup 1.0000x reference)
//
#include <hip/hip_runtime.h>
#include <math.h>

// Problem constants: L=5, B=8, n=1024, d=64
#define LL 5
#define BB 8
#define NN 1024
#define DD 64
#define LB 40              // (l,b) pairs
#define SPLIT 16           // n-split: blocks per (l,b)
#define KC (NN / SPLIT)    // 64 k-rows per block
#define ZC (2 * DD)        // Z = [X | Y], 128 columns
#define NQ 3               // stored quadrants: 0=XX, 1=XY, 2=YY (YX dup skipped)

// Workspace layout (4-byte units)
// Gp: bf16 partial quadrants, LB*SPLIT*NQ*2048 uints = 15.7 MB
// Quadrant element (row,col) -> short index (row>>1)*128 + col*2 + (row&1)
#define GP_UINTS (LB * SPLIT * NQ * 2048)
#define SP_OFF GP_UINTS                      // Sp: LB*SPLIT*ZC floats
#define RATIO_OFF (SP_OFF + LB * SPLIT * ZC) // Ratio: LB floats
#define CNT_OFF (RATIO_OFF + LB)             // cnt_lb: LB uints, then gcnt: 1 uint

typedef short short8 __attribute__((ext_vector_type(8)));   // 8 bf16 = 4 VGPRs
typedef float floatx4 __attribute__((ext_vector_type(4)));  // MFMA C/D

__device__ __forceinline__ unsigned short f2bf(float f) {
    union { float f; unsigned u; } v; v.f = f;
    const unsigned u = v.u;
    return (unsigned short)((u + 0x7FFFu + ((u >> 16) & 1u)) >> 16);  // RNE
}
__device__ __forceinline__ float bf2f(unsigned short h) {
    union { unsigned u; float f; } v; v.u = ((unsigned)h) << 16; return v.f;
}
__device__ __forceinline__ float bflo(unsigned u) {
    union { unsigned u; float f; } v; v.u = u << 16; return v.f;
}
__device__ __forceinline__ float bfhi(unsigned u) {
    union { unsigned u; float f; } v; v.u = u & 0xFFFF0000u; return v.f;
}

// LDS: bf16 K-major per Z-column, KC=64 (8 octets/col).
// Element (c,k) at short-index: c*64 + ((((k>>3) ^ ((c+(c>>4)) & 15)) & 7) << 3) + (k&7).
// Conflict-free for both b128 staging writes and b128 frag reads (R7-verified).
__device__ __forceinline__ short8 read_frag(const short* Zt, int tbase, int lane, int k0) {
    const int c = tbase + (lane & 15);
    const int o = (k0 >> 3) + (lane >> 4);
    const int oct = (o ^ ((c + (c >> 4)) & 15)) & 7;
    return *(const short8*)(Zt + c * 64 + (oct << 3));
}

// Fused kernel: per-block partial gram of a 64-row slice of Z via MFMA
// (round-0 proven body, verbatim), then per-(l,b) completion counter; the
// 16th-arriving block of each (l,b) sums that pair's partials, centers,
// Frobenius-reduces to {vxx,hxy,vyy} -> Ratio[lb]; the globally-last of the
// 40 tail blocks computes the loss. Visibility: release fence + relaxed
// atomic counter + acquire fence (HW-validated recipe, rounds 1-2).
__global__ __launch_bounds__(256) void fused_kernel(const float* __restrict__ X,
                                                    const float* __restrict__ Y,
                                                    unsigned* __restrict__ Gp,
                                                    float* __restrict__ Sp,
                                                    float* __restrict__ Ratio,
                                                    unsigned* __restrict__ cnt_lb,
                                                    unsigned* __restrict__ gcnt,
                                                    float* __restrict__ out) {
    __shared__ short Zt[ZC * KC];      // 16 KB
    __shared__ float cscr[8][ZC];      // 4 KB col-sum scratch
    __shared__ float stot[ZC];
    __shared__ float red3[4][3];
    __shared__ unsigned lflag, gflag;

    const int lb = blockIdx.y, nc = blockIdx.x, tid = threadIdx.x;
    const int r0 = nc * KC;
    const float4* X4 = (const float4*)(X + (size_t)lb * NN * DD);
    const float4* Y4 = (const float4*)(Y + (size_t)lb * NN * DD);

    // ---- load: 8 coalesced float4/thread; thread owns one k-octet ----
    const int col4 = tid & 31;
    const int rb = tid >> 5;
    float4 v[8];
#pragma unroll
    for (int m = 0; m < 8; ++m) {
        const int row = 8 * rb + m;
        v[m] = (col4 < 16) ? X4[(size_t)(r0 + row) * 16 + col4]
                           : Y4[(size_t)(r0 + row) * 16 + (col4 - 16)];
    }

    // ---- convert + pack + 4 x b128 LDS writes + bf16-consistent col sums ----
#pragma unroll
    for (int e = 0; e < 4; ++e) {
        const int c = 4 * col4 + e;
        short8 w8;
        float cs = 0.f;
#pragma unroll
        for (int m = 0; m < 8; ++m) {
            const float fv = (e == 0) ? v[m].x : (e == 1) ? v[m].y : (e == 2) ? v[m].z : v[m].w;
            const unsigned short b = f2bf(fv);
            cs += bf2f(b);
            w8[m] = (short)b;
        }
        const int oct = (rb ^ ((c + (c >> 4)) & 15)) & 7;
        *(short8*)(Zt + c * 64 + (oct << 3)) = w8;
        cscr[rb][c] = cs;
    }
    __syncthreads();
    if (tid < ZC) {
        float s = 0.f;
#pragma unroll
        for (int g = 0; g < 8; ++g) s += cscr[g][tid];
        Sp[(lb * SPLIT + nc) * ZC + tid] = s;
    }

    // ---- MFMA ----
    const int lane = tid & 63, w = tid >> 6;
    const int jbeg = (w < 2) ? 0 : 4;     // upper waves skip YX col-tiles

    floatx4 acc[2][8];
#pragma unroll
    for (int i = 0; i < 2; ++i)
#pragma unroll
        for (int j = 0; j < 8; ++j) acc[i][j] = (floatx4){0.f, 0.f, 0.f, 0.f};

#pragma unroll
    for (int k0 = 0; k0 < KC; k0 += 32) {
        short8 af[2], bfr[8];
#pragma unroll
        for (int i = 0; i < 2; ++i) af[i] = read_frag(Zt, (2 * w + i) * 16, lane, k0);
#pragma unroll
        for (int j = 0; j < 8; ++j)
            if (j >= jbeg) bfr[j] = read_frag(Zt, j * 16, lane, k0);
#pragma unroll
        for (int i = 0; i < 2; ++i)
#pragma unroll
            for (int j = 0; j < 8; ++j)
                if (j >= jbeg)
                    acc[i][j] = __builtin_amdgcn_mfma_f32_16x16x32_bf16(af[i], bfr[j], acc[i][j], 0, 0, 0);
    }

    // ---- store bf16 row-pair-packed partial quadrants ----
    // C/D: col = lane&15, row = (lane>>4)*4 + r. Rows g*4+{0,1}, g*4+{2,3} pack.
    unsigned* Gb = Gp + (size_t)(lb * SPLIT + nc) * (NQ * 2048);
    const int g = lane >> 4, cl = lane & 15;
#pragma unroll
    for (int i = 0; i < 2; ++i)
#pragma unroll
        for (int j = 0; j < 8; ++j) {
            if (j < jbeg) continue;
            const int slab = (w < 2) ? ((j < 4) ? 0 : 1) : 2;
            const int qrow0 = (w < 2 ? (2 * w + i) : (2 * (w - 2) + i)) * 16 + g * 4;
            const int qcol = (j & 3) * 16 + cl;
            const unsigned lo = (unsigned)f2bf(acc[i][j][0]) | ((unsigned)f2bf(acc[i][j][1]) << 16);
            const unsigned hi = (unsigned)f2bf(acc[i][j][2]) | ((unsigned)f2bf(acc[i][j][3]) << 16);
            Gb[slab * 2048 + (qrow0 >> 1) * 64 + qcol] = lo;
            Gb[slab * 2048 + ((qrow0 >> 1) + 1) * 64 + qcol] = hi;
        }

    // ---- per-(l,b) completion; last-arriving block reduces this pair ----
    __syncthreads();                       // drains vmcnt: all stores in L2
    if (tid == 0) {
        __threadfence();                   // release (agent scope)
        const unsigned old = atomicAdd(&cnt_lb[lb], 1u);
        lflag = (old == SPLIT - 1) ? 1u : 0u;
    }
    __syncthreads();
    if (!lflag) return;

    __threadfence();                       // acquire, per reading thread

    // col sums over all 16 slices
    if (tid < ZC) {
        float s = 0.f;
#pragma unroll
        for (int sp = 0; sp < SPLIT; ++sp) s += Sp[(lb * SPLIT + sp) * ZC + tid];
        stot[tid] = s;
    }
    __syncthreads();

    // sum partials, center (G - s s^T/n), Frobenius per quadrant
    const unsigned* Gq = Gp + (size_t)lb * SPLIT * (NQ * 2048);
    const float inv_n = 1.0f / (float)NN;
    float sq3[3] = {0.f, 0.f, 0.f};
#pragma unroll
    for (int q = 0; q < NQ; ++q) {
        const int rowbase = (q == 2) ? 64 : 0;
        const int colbase = (q == 0) ? 0 : 64;
#pragma unroll
        for (int seg = 0; seg < 4; ++seg) {
            const int u0 = seg * 512 + tid * 2;   // uint index in quadrant
            const int rp = u0 >> 6;               // row-pair
            const int c0 = u0 & 63;               // column (c0, c0+1)
            float g00 = 0.f, g10 = 0.f, g01 = 0.f, g11 = 0.f;
#pragma unroll
            for (int sp = 0; sp < SPLIT; ++sp) {
                const uint2 p = *(const uint2*)&Gq[((size_t)sp * NQ + q) * 2048 + u0];
                g00 += bflo(p.x); g10 += bfhi(p.x);
                g01 += bflo(p.y); g11 += bfhi(p.y);
            }
            const float sr0 = stot[rowbase + 2 * rp] * inv_n;
            const float sr1 = stot[rowbase + 2 * rp + 1] * inv_n;
            const float sc0 = stot[colbase + c0];
            const float sc1 = stot[colbase + c0 + 1];
            { const float cv = g00 - sr0 * sc0; sq3[q] += cv * cv; }
            { const float cv = g10 - sr1 * sc0; sq3[q] += cv * cv; }
            { const float cv = g01 - sr0 * sc1; sq3[q] += cv * cv; }
            { const float cv = g11 - sr1 * sc1; sq3[q] += cv * cv; }
        }
    }
#pragma unroll
    for (int q = 0; q < NQ; ++q)
#pragma unroll
        for (int off = 32; off; off >>= 1) sq3[q] += __shfl_down(sq3[q], off);
    if ((tid & 63) == 0) {
#pragma unroll
        for (int q = 0; q < NQ; ++q) red3[tid >> 6][q] = sq3[q];
    }
    __syncthreads();

    if (tid == 0) {
        const float vxx = red3[0][0] + red3[1][0] + red3[2][0] + red3[3][0];
        const float hxy = red3[0][1] + red3[1][1] + red3[2][1] + red3[3][1];
        const float vyy = red3[0][2] + red3[1][2] + red3[2][2] + red3[3][2];
        Ratio[lb] = fabsf(hxy / (sqrtf(vxx) * sqrtf(vyy)));
        __threadfence();                   // release Ratio[lb]
        const unsigned old = atomicAdd(gcnt, 1u);
        gflag = (old == LB - 1) ? 1u : 0u;
    }
    __syncthreads();

    // globally-last tail block: loss = mean_l(-log(mean_b(ratio)+eps))
    if (gflag && tid < 64) {
        __threadfence();                   // acquire Ratio
        float v = 0.f;
        if (tid < LB)
            v = __hip_atomic_load(Ratio + tid, __ATOMIC_RELAXED, __HIP_MEMORY_SCOPE_AGENT);
        v += __shfl_xor(v, 1);
        v += __shfl_xor(v, 2);
        v += __shfl_xor(v, 4);
        float loss = 0.f;
#pragma unroll
        for (int l = 0; l < LL; ++l) {
            const float sl = __shfl(v, l * BB);
            loss += -logf(sl * (1.0f / (float)BB) + 1e-8f);
        }
        if (tid == 0) out[0] = loss * (1.0f / (float)LL);
    }
}

extern "C" void kernel_launch(void* const* d_in, const int* in_sizes, int n_in,
                              void* d_out, int out_size, void* d_ws, size_t ws_size,
                              hipStream_t stream) {
    const float* teacher = (const float*)d_in[0];
    const float* student = (const float*)d_in[1];
    float* ws = (float*)d_ws;
    unsigned* Gp = (unsigned*)ws;
    float* Sp = ws + SP_OFF;
    float* Ratio = ws + RATIO_OFF;
    unsigned* cnt = (unsigned*)ws + CNT_OFF;      // LB per-lb counters + 1 global

    // zero the 41 counters (graph-capturable; workspace is poisoned per iter)
    hipMemsetAsync((void*)cnt, 0, (LB + 1) * sizeof(unsigned), stream);

    dim3 grid1(SPLIT, LB);
    fused_kernel<<<grid1, 256, 0, stream>>>(teacher, student, Gp, Sp, Ratio,
                                            cnt, cnt + LB, (float*)d_out);
}

// Round 4
// 87.847 us; speedup vs baseline: 1.6859x; 1.6859x over previous
//
#include <hip/hip_runtime.h>
#include <math.h>

// Problem constants: L=5, B=8, n=1024, d=64
#define LL 5
#define BB 8
#define NN 1024
#define DD 64
#define LB 40              // (l,b) pairs
#define SPLIT 16           // n-split: blocks per (l,b)
#define KC (NN / SPLIT)    // 64 k-rows per block
#define ZC (2 * DD)        // Z = [X | Y], 128 columns
#define NQ 3               // stored quadrants: 0=XX, 1=XY, 2=YY (YX dup skipped)

// Workspace layout
// Gp: bf16 partial quadrants, LB*SPLIT*NQ*4096 shorts = 15.7 MB
// Quadrant element (row,col) -> short index (row>>1)*128 + col*2 + (row&1)
#define GP_SHORTS (LB * SPLIT * NQ * 4096)
#define GP_FLOATS (GP_SHORTS / 2)
#define SP_OFF GP_FLOATS                       // Sp: LB*SPLIT*ZC floats
#define ACC_OFF (GP_FLOATS + LB * SPLIT * ZC)  // Acc2: LB x 3 x 4 segment sums (480)
#define CNT_OFF (ACC_OFF + LB * 12)            // completion counter (1 uint)

typedef short short8 __attribute__((ext_vector_type(8)));   // 8 bf16 = 4 VGPRs
typedef float floatx4 __attribute__((ext_vector_type(4)));  // MFMA C/D

__device__ __forceinline__ unsigned short f2bf(float f) {
    union { float f; unsigned u; } v; v.f = f;
    const unsigned u = v.u;
    return (unsigned short)((u + 0x7FFFu + ((u >> 16) & 1u)) >> 16);  // RNE
}
__device__ __forceinline__ float bf2f(unsigned short h) {
    union { unsigned u; float f; } v; v.u = ((unsigned)h) << 16; return v.f;
}
__device__ __forceinline__ float bflo(unsigned u) {
    union { unsigned u; float f; } v; v.u = u << 16; return v.f;
}
__device__ __forceinline__ float bfhi(unsigned u) {
    union { unsigned u; float f; } v; v.u = u & 0xFFFF0000u; return v.f;
}

// LDS: bf16 K-major per Z-column, KC=64 (8 octets/col).
// Element (c,k) at short-index: c*64 + ((((k>>3) ^ ((c+(c>>4)) & 15)) & 7) << 3) + (k&7).
// Conflict-free for both b128 staging writes and b128 frag reads (R7-verified).
__device__ __forceinline__ short8 read_frag(const short* Zt, int tbase, int lane, int k0) {
    const int c = tbase + (lane & 15);
    const int o = (k0 >> 3) + (lane >> 4);
    const int oct = (o ^ ((c + (c >> 4)) & 15)) & 7;
    return *(const short8*)(Zt + c * 64 + (oct << 3));
}

// Kernel 1: per-block partial feature-gram (Z^T Z, 128x128) of a 64-row slice
// of Z via MFMA. grid (SPLIT, LB) x 256 thr (4 waves). Waves 0,1: X row-tiles x
// all 8 col-tiles (XX + XY). Waves 2,3: Y row-tiles x Y col-tiles only (YY).
// Partials stored bf16, row-pair packed. (Round-0 proven structure, verbatim,
// plus a one-thread zero of the completion counter.)
__global__ __launch_bounds__(256) void gram_kernel(const float* __restrict__ X,
                                                   const float* __restrict__ Y,
                                                   unsigned* __restrict__ Gp,
                                                   float* __restrict__ Sp,
                                                   unsigned* __restrict__ cnt) {
    __shared__ short Zt[ZC * KC];      // 16 KB
    __shared__ float cscr[8][ZC];      // 4 KB col-sum scratch

    const int lb = blockIdx.y, nc = blockIdx.x, tid = threadIdx.x;
    const int r0 = nc * KC;
    const float4* X4 = (const float4*)(X + (size_t)lb * NN * DD);
    const float4* Y4 = (const float4*)(Y + (size_t)lb * NN * DD);

    // zero the completion counter once per launch (visible to kernel 2 at
    // the dispatch boundary; workspace is re-poisoned every iteration)
    if (blockIdx.x == 0 && blockIdx.y == 0 && tid == 0) *cnt = 0u;

    // ---- load: 8 coalesced float4/thread; thread owns one k-octet ----
    const int col4 = tid & 31;
    const int rb = tid >> 5;
    float4 v[8];
#pragma unroll
    for (int m = 0; m < 8; ++m) {
        const int row = 8 * rb + m;
        v[m] = (col4 < 16) ? X4[(size_t)(r0 + row) * 16 + col4]
                           : Y4[(size_t)(r0 + row) * 16 + (col4 - 16)];
    }

    // ---- convert + pack + 4 x b128 LDS writes + bf16-consistent col sums ----
#pragma unroll
    for (int e = 0; e < 4; ++e) {
        const int c = 4 * col4 + e;
        short8 w8;
        float cs = 0.f;
#pragma unroll
        for (int m = 0; m < 8; ++m) {
            const float fv = (e == 0) ? v[m].x : (e == 1) ? v[m].y : (e == 2) ? v[m].z : v[m].w;
            const unsigned short b = f2bf(fv);
            cs += bf2f(b);
            w8[m] = (short)b;
        }
        const int oct = (rb ^ ((c + (c >> 4)) & 15)) & 7;
        *(short8*)(Zt + c * 64 + (oct << 3)) = w8;
        cscr[rb][c] = cs;
    }
    __syncthreads();
    if (tid < ZC) {
        float s = 0.f;
#pragma unroll
        for (int g = 0; g < 8; ++g) s += cscr[g][tid];
        Sp[(lb * SPLIT + nc) * ZC + tid] = s;
    }

    // ---- MFMA ----
    const int lane = tid & 63, w = tid >> 6;
    const int jbeg = (w < 2) ? 0 : 4;     // upper waves skip YX col-tiles

    floatx4 acc[2][8];
#pragma unroll
    for (int i = 0; i < 2; ++i)
#pragma unroll
        for (int j = 0; j < 8; ++j) acc[i][j] = (floatx4){0.f, 0.f, 0.f, 0.f};

#pragma unroll
    for (int k0 = 0; k0 < KC; k0 += 32) {
        short8 af[2], bfr[8];
#pragma unroll
        for (int i = 0; i < 2; ++i) af[i] = read_frag(Zt, (2 * w + i) * 16, lane, k0);
#pragma unroll
        for (int j = 0; j < 8; ++j)
            if (j >= jbeg) bfr[j] = read_frag(Zt, j * 16, lane, k0);
#pragma unroll
        for (int i = 0; i < 2; ++i)
#pragma unroll
            for (int j = 0; j < 8; ++j)
                if (j >= jbeg)
                    acc[i][j] = __builtin_amdgcn_mfma_f32_16x16x32_bf16(af[i], bfr[j], acc[i][j], 0, 0, 0);
    }

    // ---- store bf16 row-pair-packed partial quadrants ----
    // C/D: col = lane&15, row = (lane>>4)*4 + r. Rows g*4+{0,1}, g*4+{2,3} pack.
    unsigned* Gb = Gp + (size_t)(lb * SPLIT + nc) * (NQ * 2048);
    const int g = lane >> 4, cl = lane & 15;
#pragma unroll
    for (int i = 0; i < 2; ++i)
#pragma unroll
        for (int j = 0; j < 8; ++j) {
            if (j < jbeg) continue;
            const int slab = (w < 2) ? ((j < 4) ? 0 : 1) : 2;
            const int qrow0 = (w < 2 ? (2 * w + i) : (2 * (w - 2) + i)) * 16 + g * 4;
            const int qcol = (j & 3) * 16 + cl;
            const unsigned lo = (unsigned)f2bf(acc[i][j][0]) | ((unsigned)f2bf(acc[i][j][1]) << 16);
            const unsigned hi = (unsigned)f2bf(acc[i][j][2]) | ((unsigned)f2bf(acc[i][j][3]) << 16);
            Gb[slab * 2048 + (qrow0 >> 1) * 64 + qcol] = lo;
            Gb[slab * 2048 + ((qrow0 >> 1) + 1) * 64 + qcol] = hi;
        }
}

// Kernel 2: sum SPLIT bf16 partials, center (G - s s^T/n), Frobenius-reduce.
// grid = LB*NQ*4 = 480 blocks x 256 thr. Plain deterministic store per block into
// its own Acc2 slot, then a completion counter; the LAST block computes the loss
// (fuses former kernel 3 — fence/atomic-load recipe HW-validated in rounds 1-2).
__global__ __launch_bounds__(256) void reduce_kernel(const unsigned* __restrict__ Gp,
                                                     const float* __restrict__ Sp,
                                                     float* __restrict__ Acc2,
                                                     unsigned* __restrict__ cnt,
                                                     float* __restrict__ out) {
    const int b = blockIdx.x;
    const int lb = b / (NQ * 4);
    const int rem = b % (NQ * 4);
    const int q = rem >> 2, seg = rem & 3;
    const int tid = threadIdx.x;

    __shared__ float stot[ZC];
    __shared__ float red[4];
    __shared__ unsigned lastflag;

    if (tid < ZC) {
        float s = 0.f;
#pragma unroll
        for (int sp = 0; sp < SPLIT; ++sp) s += Sp[(lb * SPLIT + sp) * ZC + tid];
        stot[tid] = s;
    }
    __syncthreads();

    const int u0 = seg * 512 + tid * 2;      // uint index within 2048-uint quadrant
    const int rp = u0 >> 6;                  // row-pair
    const int c0 = u0 & 63;                  // column (c0, c0+1)

    float g00 = 0.f, g10 = 0.f, g01 = 0.f, g11 = 0.f;   // [row&1][col-e]
#pragma unroll
    for (int sp = 0; sp < SPLIT; ++sp) {
        const uint2 p = *(const uint2*)&Gp[((size_t)(lb * SPLIT + sp) * NQ + q) * 2048 + u0];
        g00 += bflo(p.x); g10 += bfhi(p.x);
        g01 += bflo(p.y); g11 += bfhi(p.y);
    }
    const int rowbase = (q == 2) ? 64 : 0;
    const int colbase = (q == 0) ? 0 : 64;
    const float inv_n = 1.0f / (float)NN;
    const float sr0 = stot[rowbase + 2 * rp] * inv_n;
    const float sr1 = stot[rowbase + 2 * rp + 1] * inv_n;
    const float sc0 = stot[colbase + c0];
    const float sc1 = stot[colbase + c0 + 1];
    float sq = 0.f;
    { const float cv = g00 - sr0 * sc0; sq += cv * cv; }
    { const float cv = g10 - sr1 * sc0; sq += cv * cv; }
    { const float cv = g01 - sr0 * sc1; sq += cv * cv; }
    { const float cv = g11 - sr1 * sc1; sq += cv * cv; }

#pragma unroll
    for (int off = 32; off; off >>= 1) sq += __shfl_down(sq, off);
    const int wave = tid >> 6;
    if ((tid & 63) == 0) red[wave] = sq;
    __syncthreads();

    if (tid == 0) {
        Acc2[lb * 12 + q * 4 + seg] = red[0] + red[1] + red[2] + red[3];
        __threadfence();
        const unsigned old = atomicAdd(cnt, 1u);
        lastflag = (old == (unsigned)(LB * NQ * 4 - 1)) ? 1u : 0u;
    }
    __syncthreads();

    // last block: ratio per (l,b), mean over b, -log, mean over l
    if (lastflag && tid < 64) {
        __threadfence();
        float v = 0.f;
        if (tid < LB) {
            float vxx = 0.f, hxy = 0.f, vyy = 0.f;
#pragma unroll
            for (int s = 0; s < 4; ++s) {
                vxx += __hip_atomic_load(Acc2 + tid * 12 + s, __ATOMIC_RELAXED, __HIP_MEMORY_SCOPE_AGENT);
                hxy += __hip_atomic_load(Acc2 + tid * 12 + 4 + s, __ATOMIC_RELAXED, __HIP_MEMORY_SCOPE_AGENT);
                vyy += __hip_atomic_load(Acc2 + tid * 12 + 8 + s, __ATOMIC_RELAXED, __HIP_MEMORY_SCOPE_AGENT);
            }
            v = fabsf(hxy / (sqrtf(vxx) * sqrtf(vyy)));
        }
        v += __shfl_xor(v, 1);
        v += __shfl_xor(v, 2);
        v += __shfl_xor(v, 4);
        float loss = 0.f;
#pragma unroll
        for (int l = 0; l < LL; ++l) {
            const float sl = __shfl(v, l * BB);
            loss += -logf(sl * (1.0f / (float)BB) + 1e-8f);
        }
        if (tid == 0) out[0] = loss * (1.0f / (float)LL);
    }
}

extern "C" void kernel_launch(void* const* d_in, const int* in_sizes, int n_in,
                              void* d_out, int out_size, void* d_ws, size_t ws_size,
                              hipStream_t stream) {
    const float* teacher = (const float*)d_in[0];
    const float* student = (const float*)d_in[1];
    float* ws = (float*)d_ws;
    unsigned* Gp = (unsigned*)ws;
    float* Sp = ws + SP_OFF;
    float* Acc2 = ws + ACC_OFF;
    unsigned* cnt = (unsigned*)(ws + CNT_OFF);

    dim3 grid1(SPLIT, LB);
    gram_kernel<<<grid1, 256, 0, stream>>>(teacher, student, Gp, Sp, cnt);
    reduce_kernel<<<LB * NQ * 4, 256, 0, stream>>>(Gp, Sp, Acc2, cnt, (float*)d_out);
}

// Round 5
// 83.896 us; speedup vs baseline: 1.7653x; 1.0471x over previous
//
#include <hip/hip_runtime.h>
#include <math.h>

// Problem constants: L=5, B=8, n=1024, d=64
#define LL 5
#define BB 8
#define NN 1024
#define DD 64
#define LB 40              // (l,b) pairs
#define SPLIT 16           // n-split: blocks per (l,b)
#define KC (NN / SPLIT)    // 64 k-rows per block
#define ZC (2 * DD)        // Z = [X | Y], 128 columns
#define NQ 3               // stored quadrants: 0=XX, 1=XY, 2=YY (YX dup skipped)

// Workspace layout
// Gp: bf16 partial quadrants, LB*SPLIT*NQ*4096 shorts = 15.7 MB
// Quadrant element (row,col) -> short index (row>>1)*128 + col*2 + (row&1)
#define GP_SHORTS (LB * SPLIT * NQ * 4096)
#define GP_FLOATS (GP_SHORTS / 2)
#define SP_OFF GP_FLOATS                       // Sp: LB*SPLIT*ZC floats
#define ACC_OFF (GP_FLOATS + LB * SPLIT * ZC)  // Acc2: LB x 3 x 4 segment sums (480)
#define CNT_OFF (ACC_OFF + LB * 12)            // completion counter (1 uint)

typedef short short8 __attribute__((ext_vector_type(8)));   // 8 bf16 = 4 VGPRs
typedef float floatx4 __attribute__((ext_vector_type(4)));  // MFMA C/D

__device__ __forceinline__ unsigned short f2bf(float f) {
    union { float f; unsigned u; } v; v.f = f;
    const unsigned u = v.u;
    return (unsigned short)((u + 0x7FFFu + ((u >> 16) & 1u)) >> 16);  // RNE
}
__device__ __forceinline__ float bf2f(unsigned short h) {
    union { unsigned u; float f; } v; v.u = ((unsigned)h) << 16; return v.f;
}
__device__ __forceinline__ float bflo(unsigned u) {
    union { unsigned u; float f; } v; v.u = u << 16; return v.f;
}
__device__ __forceinline__ float bfhi(unsigned u) {
    union { unsigned u; float f; } v; v.u = u & 0xFFFF0000u; return v.f;
}

// LDS: bf16 K-major per Z-column, KC=64 (8 octets/col).
// Element (c,k) at short-index: c*64 + ((((k>>3) ^ ((c+(c>>4)) & 15)) & 7) << 3) + (k&7).
// Conflict-free for both b128 staging writes and b128 frag reads (R7-verified).
__device__ __forceinline__ short8 read_frag(const short* Zt, int tbase, int lane, int k0) {
    const int c = tbase + (lane & 15);
    const int o = (k0 >> 3) + (lane >> 4);
    const int oct = (o ^ ((c + (c >> 4)) & 15)) & 7;
    return *(const short8*)(Zt + c * 64 + (oct << 3));
}

// XCD-locality swizzle (single variable changed this round):
// MI355X dispatches blocks round-robin across the 8 XCDs in linear-id order
// (id & 7 -> XCD, heuristic). We remap so ALL work of a given (l,b) pair —
// 16 gram slices here, 12 reduce blocks in kernel 2 — lands on XCD lb%8.
// Partials (384 KB/pair, 5 pairs * 384 KB = 1.9 MB per XCD) are then written
// and re-read within one XCD's 4 MB L2. Bijective: perf-only, not correctness.

// Kernel 1: per-block partial feature-gram (Z^T Z, 128x128) of a 64-row slice
// of Z via MFMA. grid 640 x 256 thr (4 waves). Waves 0,1: X row-tiles x
// all 8 col-tiles (XX + XY). Waves 2,3: Y row-tiles x Y col-tiles only (YY).
// Partials stored bf16, row-pair packed. (Round-0 proven body, verbatim.)
__global__ __launch_bounds__(256) void gram_kernel(const float* __restrict__ X,
                                                   const float* __restrict__ Y,
                                                   unsigned* __restrict__ Gp,
                                                   float* __restrict__ Sp,
                                                   unsigned* __restrict__ cnt) {
    __shared__ short Zt[ZC * KC];      // 16 KB
    __shared__ float cscr[8][ZC];      // 4 KB col-sum scratch

    const int id = blockIdx.x, tid = threadIdx.x;
    const int xcd = id & 7, jj = id >> 3;      // jj in 0..79
    const int lb = xcd + 8 * (jj % 5);         // all 16 slices of lb on XCD lb%8
    const int nc = jj / 5;                     // 0..15, each exactly once per lb
    const int r0 = nc * KC;
    const float4* X4 = (const float4*)(X + (size_t)lb * NN * DD);
    const float4* Y4 = (const float4*)(Y + (size_t)lb * NN * DD);

    // zero the completion counter once per launch (visible to kernel 2 at
    // the dispatch boundary; workspace is re-poisoned every iteration)
    if (id == 0 && tid == 0) *cnt = 0u;

    // ---- load: 8 coalesced float4/thread; thread owns one k-octet ----
    const int col4 = tid & 31;
    const int rb = tid >> 5;
    float4 v[8];
#pragma unroll
    for (int m = 0; m < 8; ++m) {
        const int row = 8 * rb + m;
        v[m] = (col4 < 16) ? X4[(size_t)(r0 + row) * 16 + col4]
                           : Y4[(size_t)(r0 + row) * 16 + (col4 - 16)];
    }

    // ---- convert + pack + 4 x b128 LDS writes + bf16-consistent col sums ----
#pragma unroll
    for (int e = 0; e < 4; ++e) {
        const int c = 4 * col4 + e;
        short8 w8;
        float cs = 0.f;
#pragma unroll
        for (int m = 0; m < 8; ++m) {
            const float fv = (e == 0) ? v[m].x : (e == 1) ? v[m].y : (e == 2) ? v[m].z : v[m].w;
            const unsigned short b = f2bf(fv);
            cs += bf2f(b);
            w8[m] = (short)b;
        }
        const int oct = (rb ^ ((c + (c >> 4)) & 15)) & 7;
        *(short8*)(Zt + c * 64 + (oct << 3)) = w8;
        cscr[rb][c] = cs;
    }
    __syncthreads();
    if (tid < ZC) {
        float s = 0.f;
#pragma unroll
        for (int g = 0; g < 8; ++g) s += cscr[g][tid];
        Sp[(lb * SPLIT + nc) * ZC + tid] = s;
    }

    // ---- MFMA ----
    const int lane = tid & 63, w = tid >> 6;
    const int jbeg = (w < 2) ? 0 : 4;     // upper waves skip YX col-tiles

    floatx4 acc[2][8];
#pragma unroll
    for (int i = 0; i < 2; ++i)
#pragma unroll
        for (int j = 0; j < 8; ++j) acc[i][j] = (floatx4){0.f, 0.f, 0.f, 0.f};

#pragma unroll
    for (int k0 = 0; k0 < KC; k0 += 32) {
        short8 af[2], bfr[8];
#pragma unroll
        for (int i = 0; i < 2; ++i) af[i] = read_frag(Zt, (2 * w + i) * 16, lane, k0);
#pragma unroll
        for (int j = 0; j < 8; ++j)
            if (j >= jbeg) bfr[j] = read_frag(Zt, j * 16, lane, k0);
#pragma unroll
        for (int i = 0; i < 2; ++i)
#pragma unroll
            for (int j = 0; j < 8; ++j)
                if (j >= jbeg)
                    acc[i][j] = __builtin_amdgcn_mfma_f32_16x16x32_bf16(af[i], bfr[j], acc[i][j], 0, 0, 0);
    }

    // ---- store bf16 row-pair-packed partial quadrants ----
    // C/D: col = lane&15, row = (lane>>4)*4 + r. Rows g*4+{0,1}, g*4+{2,3} pack.
    unsigned* Gb = Gp + (size_t)(lb * SPLIT + nc) * (NQ * 2048);
    const int g = lane >> 4, cl = lane & 15;
#pragma unroll
    for (int i = 0; i < 2; ++i)
#pragma unroll
        for (int j = 0; j < 8; ++j) {
            if (j < jbeg) continue;
            const int slab = (w < 2) ? ((j < 4) ? 0 : 1) : 2;
            const int qrow0 = (w < 2 ? (2 * w + i) : (2 * (w - 2) + i)) * 16 + g * 4;
            const int qcol = (j & 3) * 16 + cl;
            const unsigned lo = (unsigned)f2bf(acc[i][j][0]) | ((unsigned)f2bf(acc[i][j][1]) << 16);
            const unsigned hi = (unsigned)f2bf(acc[i][j][2]) | ((unsigned)f2bf(acc[i][j][3]) << 16);
            Gb[slab * 2048 + (qrow0 >> 1) * 64 + qcol] = lo;
            Gb[slab * 2048 + ((qrow0 >> 1) + 1) * 64 + qcol] = hi;
        }
}

// Kernel 2: sum SPLIT bf16 partials, center (G - s s^T/n), Frobenius-reduce.
// grid = LB*NQ*4 = 480 blocks x 256 thr, XCD-swizzled to match kernel 1's
// placement (12 blocks of lb on XCD lb%8 -> partial reads hit local L2).
// Plain deterministic store per block into its own Acc2 slot, then a
// completion counter; the LAST block computes the loss (recipe HW-validated
// in rounds 1-2).
__global__ __launch_bounds__(256) void reduce_kernel(const unsigned* __restrict__ Gp,
                                                     const float* __restrict__ Sp,
                                                     float* __restrict__ Acc2,
                                                     unsigned* __restrict__ cnt,
                                                     float* __restrict__ out) {
    const int id = blockIdx.x;
    const int xcd = id & 7, jj = id >> 3;      // jj in 0..59
    const int lb = xcd + 8 * (jj % 5);         // same XCD as lb's gram slices
    const int rem = jj / 5;                    // 0..11, each exactly once per lb
    const int q = rem >> 2, seg = rem & 3;
    const int tid = threadIdx.x;

    __shared__ float stot[ZC];
    __shared__ float red[4];
    __shared__ unsigned lastflag;

    if (tid < ZC) {
        float s = 0.f;
#pragma unroll
        for (int sp = 0; sp < SPLIT; ++sp) s += Sp[(lb * SPLIT + sp) * ZC + tid];
        stot[tid] = s;
    }
    __syncthreads();

    const int u0 = seg * 512 + tid * 2;      // uint index within 2048-uint quadrant
    const int rp = u0 >> 6;                  // row-pair
    const int c0 = u0 & 63;                  // column (c0, c0+1)

    float g00 = 0.f, g10 = 0.f, g01 = 0.f, g11 = 0.f;   // [row&1][col-e]
#pragma unroll
    for (int sp = 0; sp < SPLIT; ++sp) {
        const uint2 p = *(const uint2*)&Gp[((size_t)(lb * SPLIT + sp) * NQ + q) * 2048 + u0];
        g00 += bflo(p.x); g10 += bfhi(p.x);
        g01 += bflo(p.y); g11 += bfhi(p.y);
    }
    const int rowbase = (q == 2) ? 64 : 0;
    const int colbase = (q == 0) ? 0 : 64;
    const float inv_n = 1.0f / (float)NN;
    const float sr0 = stot[rowbase + 2 * rp] * inv_n;
    const float sr1 = stot[rowbase + 2 * rp + 1] * inv_n;
    const float sc0 = stot[colbase + c0];
    const float sc1 = stot[colbase + c0 + 1];
    float sq = 0.f;
    { const float cv = g00 - sr0 * sc0; sq += cv * cv; }
    { const float cv = g10 - sr1 * sc0; sq += cv * cv; }
    { const float cv = g01 - sr0 * sc1; sq += cv * cv; }
    { const float cv = g11 - sr1 * sc1; sq += cv * cv; }

#pragma unroll
    for (int off = 32; off; off >>= 1) sq += __shfl_down(sq, off);
    const int wave = tid >> 6;
    if ((tid & 63) == 0) red[wave] = sq;
    __syncthreads();

    if (tid == 0) {
        Acc2[lb * 12 + q * 4 + seg] = red[0] + red[1] + red[2] + red[3];
        __threadfence();
        const unsigned old = atomicAdd(cnt, 1u);
        lastflag = (old == (unsigned)(LB * NQ * 4 - 1)) ? 1u : 0u;
    }
    __syncthreads();

    // last block: ratio per (l,b), mean over b, -log, mean over l
    if (lastflag && tid < 64) {
        __threadfence();
        float v = 0.f;
        if (tid < LB) {
            float vxx = 0.f, hxy = 0.f, vyy = 0.f;
#pragma unroll
            for (int s = 0; s < 4; ++s) {
                vxx += __hip_atomic_load(Acc2 + tid * 12 + s, __ATOMIC_RELAXED, __HIP_MEMORY_SCOPE_AGENT);
                hxy += __hip_atomic_load(Acc2 + tid * 12 + 4 + s, __ATOMIC_RELAXED, __HIP_MEMORY_SCOPE_AGENT);
                vyy += __hip_atomic_load(Acc2 + tid * 12 + 8 + s, __ATOMIC_RELAXED, __HIP_MEMORY_SCOPE_AGENT);
            }
            v = fabsf(hxy / (sqrtf(vxx) * sqrtf(vyy)));
        }
        v += __shfl_xor(v, 1);
        v += __shfl_xor(v, 2);
        v += __shfl_xor(v, 4);
        float loss = 0.f;
#pragma unroll
        for (int l = 0; l < LL; ++l) {
            const float sl = __shfl(v, l * BB);
            loss += -logf(sl * (1.0f / (float)BB) + 1e-8f);
        }
        if (tid == 0) out[0] = loss * (1.0f / (float)LL);
    }
}

extern "C" void kernel_launch(void* const* d_in, const int* in_sizes, int n_in,
                              void* d_out, int out_size, void* d_ws, size_t ws_size,
                              hipStream_t stream) {
    const float* teacher = (const float*)d_in[0];
    const float* student = (const float*)d_in[1];
    float* ws = (float*)d_ws;
    unsigned* Gp = (unsigned*)ws;
    float* Sp = ws + SP_OFF;
    float* Acc2 = ws + ACC_OFF;
    unsigned* cnt = (unsigned*)(ws + CNT_OFF);

    gram_kernel<<<SPLIT * LB, 256, 0, stream>>>(teacher, student, Gp, Sp, cnt);
    reduce_kernel<<<LB * NQ * 4, 256, 0, stream>>>(Gp, Sp, Acc2, cnt, (float*)d_out);
}